// Round 3
// baseline (466.570 us; speedup 1.0000x reference)
//
#include <hip/hip_runtime.h>

// Problem constants (from reference): grid (1,4,1024,1024) f32,
// out (1,4,4096,4096) f32, coordinate_start int32[2] in [0,512).
constexpr int C    = 4;
constexpr int GH   = 1024;
constexpr int GW   = 1024;
constexpr int HOUT = 4096;
constexpr int WOUT = 4096;

// Clang native vector type — __builtin_nontemporal_store requires this
// (HIP's float4 class is invalid for the builtin).
typedef float vfloat4 __attribute__((ext_vector_type(4)));

// Sample points land (up to fp32 rounding) on integer texels; we still do the
// full fp32 bilinear to track the reference's rounding. Reciprocal-multiply
// instead of divide: error ~2e-6 << 6.2e-5 threshold (measured absmax 1.5e-5).
//
// R1 lesson: plain float4 stores triggered L2 write-allocate — FETCH_SIZE
// equaled WRITE_SIZE (262 MB of useless read-for-ownership). Output is
// write-once, so store it non-temporally.

__global__ __launch_bounds__(256) void grid_sample_k(
    const float* __restrict__ grid,
    const int*   __restrict__ cstart,
    vfloat4*     __restrict__ out4)
{
    const int tid = blockIdx.x * blockDim.x + threadIdx.x;
    // tid -> (c, oh, ow4); WOUT/4 = 1024 float4's per row
    const int ow4 = tid & 1023;
    const int r   = tid >> 10;
    const int oh  = r & (HOUT - 1);
    const int c   = r >> 12;

    const int sx = cstart[0];
    const int sy = cstart[1];

    constexpr float kInvOff = 1.0f / 511.5f;

    // y depends only on oh — one computation per thread
    const int my = (sy + oh) & (GH - 1);
    const float fy = ((float)my - 511.5f) * kInvOff;
    float y = (fy + 1.0f) * 0.5f * (float)(GH - 1);
    y = fminf(fmaxf(y, 0.0f), (float)(GH - 1));
    const float y0f = floorf(y);
    const float wy  = y - y0f;
    const int   y0  = (int)y0f;
    const int   y1  = min(y0 + 1, GH - 1);

    const float* __restrict__ gp   = grid + (size_t)c * (GH * GW);
    const float* __restrict__ row0 = gp + (size_t)y0 * GW;
    const float* __restrict__ row1 = gp + (size_t)y1 * GW;

    const int owbase = ow4 << 2;
    vfloat4 res;
#pragma unroll
    for (int i = 0; i < 4; ++i) {
        const int mx = (sx + owbase + i) & (GW - 1);
        const float fx = ((float)mx - 511.5f) * kInvOff;
        float x = (fx + 1.0f) * 0.5f * (float)(GW - 1);
        x = fminf(fmaxf(x, 0.0f), (float)(GW - 1));
        const float x0f = floorf(x);
        const float wx  = x - x0f;
        const int   x0  = (int)x0f;
        const int   x1  = min(x0 + 1, GW - 1);

        const float v00 = row0[x0];
        const float v01 = row0[x1];
        const float v10 = row1[x0];
        const float v11 = row1[x1];

        const float top = v00 * (1.0f - wx) + v01 * wx;
        const float bot = v10 * (1.0f - wx) + v11 * wx;
        res[i] = top * (1.0f - wy) + bot * wy;
    }

    // Non-temporal: avoid L2 write-allocate RFO on the write-once output.
    __builtin_nontemporal_store(res, &out4[tid]);
}

extern "C" void kernel_launch(void* const* d_in, const int* in_sizes, int n_in,
                              void* d_out, int out_size, void* d_ws, size_t ws_size,
                              hipStream_t stream)
{
    const float* grid   = (const float*)d_in[0];
    const int*   cstart = (const int*)d_in[1];
    // d_in[2..5] are h, w, support_resolution_h, support_resolution_w — fixed
    // at 4096/4096/1024/1024 per the reference module; baked in as constexpr.
    vfloat4* out = (vfloat4*)d_out;

    const int total4 = C * HOUT * (WOUT / 4);  // 16,777,216 float4 stores
    const int block  = 256;
    const int nblk   = total4 / block;         // 65,536 blocks
    grid_sample_k<<<nblk, block, 0, stream>>>(grid, cstart, out);
}

// Round 5
// 323.932 us; speedup vs baseline: 1.4403x; 1.4403x over previous
//
#include <hip/hip_runtime.h>

// grid (1,4,1024,1024) f32 -> out (1,4,4096,4096) f32; cstart int32[2] in [0,512).
constexpr int C    = 4;
constexpr int GH   = 1024;
constexpr int GW   = 1024;
constexpr int HOUT = 4096;
constexpr int WOUT = 4096;

typedef float vfloat4 __attribute__((ext_vector_type(4)));

// R3 post-mortem: 16 scalar gathers/thread at 16B lane-stride = ~544 L1
// 32B-sector transactions per wave = 232us floor (matches measured 244us).
// This version loads the needed grid window as contiguous dwordx4 blocks
// (lane-consecutive, 100% sector utilization): 4 loads/thread (6 if sx%4==0),
// ~160 sectors/wave -> ~3.5x. Arithmetic chain is copied verbatim from R3
// (same fp32 expression order), selecting identical row elements via static
// window offsets -> bit-identical output (absmax 1.525879e-05).

// 12-float window (three vfloat4 blocks); c unused on the 2-block path.
struct Win12 { vfloat4 a, b, c; };
template <int J> __device__ __forceinline__ float wget(const Win12& w) {
    static_assert(J >= 0 && J < 12, "window index");
    if constexpr (J < 4)      return w.a[J];
    else if constexpr (J < 8) return w.b[J - 4];
    else                      return w.c[J - 8];
}

// One output pixel; Q,I compile-time so all wget indices are constants.
// Window invariant: w[Q+I] == row[(mbase+I)&1023].
template <int Q, int I>
__device__ __forceinline__ float evalpix(const Win12& w0, const Win12& w1,
                                         int mbase, float wy) {
    constexpr float kInvOff = 1.0f / 511.5f;
    const int mx = (mbase + I) & (GW - 1);
    const float fx = ((float)mx - 511.5f) * kInvOff;
    float x = (fx + 1.0f) * 0.5f * (float)(GW - 1);
    x = fminf(fmaxf(x, 0.0f), (float)(GW - 1));
    const float x0f = floorf(x);
    const float wx  = x - x0f;
    const int   ix0 = (int)x0f;              // == mx or mx-1 (never <0: x>=0)

    const float wm1_0 = wget<Q + I - 1>(w0);
    const float wc_0  = wget<Q + I    >(w0);
    const float wp1_0 = wget<Q + I + 1>(w0);
    const float wm1_1 = wget<Q + I - 1>(w1);
    const float wc_1  = wget<Q + I    >(w1);
    const float wp1_1 = wget<Q + I + 1>(w1);

    const bool lo   = (ix0 != mx);           // floor rounded down to mx-1
    const bool edge = (mx == GW - 1);        // x1 clamp at right border

    const float v00 = lo ? wm1_0 : wc_0;
    const float v01 = lo ? wc_0 : (edge ? wc_0 : wp1_0);
    const float v10 = lo ? wm1_1 : wc_1;
    const float v11 = lo ? wc_1 : (edge ? wc_1 : wp1_1);

    const float top = v00 * (1.0f - wx) + v01 * wx;
    const float bot = v10 * (1.0f - wx) + v11 * wx;
    return top * (1.0f - wy) + bot * wy;
}

template <int Q>
__device__ __forceinline__ vfloat4 eval4(const Win12& w0, const Win12& w1,
                                         int mbase, float wy) {
    vfloat4 res;
    res[0] = evalpix<Q, 0>(w0, w1, mbase, wy);
    res[1] = evalpix<Q, 1>(w0, w1, mbase, wy);
    res[2] = evalpix<Q, 2>(w0, w1, mbase, wy);
    res[3] = evalpix<Q, 3>(w0, w1, mbase, wy);
    return res;
}

__global__ __launch_bounds__(256) void grid_sample_k(
    const float* __restrict__ grid,
    const int*   __restrict__ cstart,
    vfloat4*     __restrict__ out4)
{
    // XCD-aware decomposition: 65,536 blocks; blockIdx%8 (assumed XCD id)
    // selects a 128-grid-row slab so each XCD's 4MB L2 holds its ~2.1MB of
    // grid rows (4ch x 129 rows) -> each grid line fetched ~once per device.
    const int x    = blockIdx.x & 7;          // XCD slab
    const int s    = blockIdx.x >> 3;
    const int chunk = s & 3;                  // quarter of an output row
    const int rep   = (s >> 2) & 3;           // which 1024-row repeat
    const int g     = (x << 7) | ((s >> 4) & 127);  // grid row 0..1023
    const int c     = s >> 11;                // channel 0..3

    const int sx = cstart[0];
    const int sy = cstart[1];

    const int oh = ((g - sy) & (GH - 1)) + (rep << 10);   // output row

    // y chain (verbatim from R3; my == g for this block)
    constexpr float kInvOff = 1.0f / 511.5f;
    const int my = g;
    const float fy = ((float)my - 511.5f) * kInvOff;
    float y = (fy + 1.0f) * 0.5f * (float)(GH - 1);
    y = fminf(fmaxf(y, 0.0f), (float)(GH - 1));
    const float y0f = floorf(y);
    const float wy  = y - y0f;
    const int   y0  = (int)y0f;
    const int   y1  = min(y0 + 1, GH - 1);

    const float* gp = grid + (size_t)c * (GH * GW);
    const vfloat4* __restrict__ row0 = (const vfloat4*)(gp + (size_t)y0 * GW);
    const vfloat4* __restrict__ row1 = (const vfloat4*)(gp + (size_t)y1 * GW);

    const int tid   = threadIdx.x;
    const int ow    = (chunk << 10) + (tid << 2);   // first of 4 output px
    const int mbase = sx + ow;                      // pre-mod grid col
    const int B     = (sx >> 2) + (chunk << 8) + tid;  // aligned block index
    const int p     = sx & 3;                       // uniform phase

    const int b0 = B & 255;
    const int b1 = (B + 1) & 255;

    vfloat4 res;
    if (p == 0) {
        // window must reach row[mx-1] -> needs block B-1 too (3 blocks)
        const int bm = (B + 255) & 255;
        Win12 w0, w1;
        w0.a = row0[bm]; w0.b = row0[b0]; w0.c = row0[b1];
        w1.a = row1[bm]; w1.b = row1[b0]; w1.c = row1[b1];
        res = eval4<4>(w0, w1, mbase, wy);
    } else {
        Win12 w0, w1;
        w0.a = row0[b0]; w0.b = row0[b1]; w0.c = w0.b;
        w1.a = row1[b0]; w1.b = row1[b1]; w1.c = w1.b;
        if (p == 1)      res = eval4<1>(w0, w1, mbase, wy);
        else if (p == 2) res = eval4<2>(w0, w1, mbase, wy);
        else             res = eval4<3>(w0, w1, mbase, wy);
    }

    const int oidx = (c * HOUT + oh) * (WOUT / 4) + (chunk << 8) + tid;
    __builtin_nontemporal_store(res, &out4[oidx]);
}

extern "C" void kernel_launch(void* const* d_in, const int* in_sizes, int n_in,
                              void* d_out, int out_size, void* d_ws, size_t ws_size,
                              hipStream_t stream)
{
    const float* grid   = (const float*)d_in[0];
    const int*   cstart = (const int*)d_in[1];
    vfloat4* out = (vfloat4*)d_out;

    const int nblk = C * HOUT * (WOUT / 4) / 256;   // 65,536 blocks
    grid_sample_k<<<nblk, 256, 0, stream>>>(grid, cstart, out);
}

// Round 6
// 290.617 us; speedup vs baseline: 1.6054x; 1.1146x over previous
//
#include <hip/hip_runtime.h>

// grid (1,4,1024,1024) f32 -> out (1,4,4096,4096) f32; cstart int32[2] in [0,512).
constexpr int C    = 4;
constexpr int GH   = 1024;
constexpr int GW   = 1024;
constexpr int HOUT = 4096;
constexpr int WOUT = 4096;

typedef float vfloat4 __attribute__((ext_vector_type(4)));

// R5 post-mortem: kernel ~105us, L1 sector-bound (loads 4-6 dwordx4/thread).
// Key structural fact: output is PERIODIC — px (oh,ow) and (oh+1024r, ow+1024k)
// sample the same grid texel (mx=(sx+ow)&1023, my=(sy+oh)&1023). The 268MB
// output is a 4x4 tiling of a 16MB-per-... unique 1024x1024 tile per channel.
// So: compute each unique 4-px group ONCE, issue 16 replicated NT stores.
// Loads amortize 16x -> HBM-write-bound (~268MB @ 6.4TB/s ~ 45us).
// Eval chain kept verbatim from R5 -> bit-identical (absmax 1.525879e-05).

// 12-float window (three vfloat4 blocks); c unused on the 2-block path.
struct Win12 { vfloat4 a, b, c; };
template <int J> __device__ __forceinline__ float wget(const Win12& w) {
    static_assert(J >= 0 && J < 12, "window index");
    if constexpr (J < 4)      return w.a[J];
    else if constexpr (J < 8) return w.b[J - 4];
    else                      return w.c[J - 8];
}

// One output pixel; Q,I compile-time so all wget indices are constants.
// Window invariant: w[Q+I] == row[(mbase+I)&1023].
template <int Q, int I>
__device__ __forceinline__ float evalpix(const Win12& w0, const Win12& w1,
                                         int mbase, float wy) {
    constexpr float kInvOff = 1.0f / 511.5f;
    const int mx = (mbase + I) & (GW - 1);
    const float fx = ((float)mx - 511.5f) * kInvOff;
    float x = (fx + 1.0f) * 0.5f * (float)(GW - 1);
    x = fminf(fmaxf(x, 0.0f), (float)(GW - 1));
    const float x0f = floorf(x);
    const float wx  = x - x0f;
    const int   ix0 = (int)x0f;              // == mx or mx-1 (never <0: x>=0)

    const float wm1_0 = wget<Q + I - 1>(w0);
    const float wc_0  = wget<Q + I    >(w0);
    const float wp1_0 = wget<Q + I + 1>(w0);
    const float wm1_1 = wget<Q + I - 1>(w1);
    const float wc_1  = wget<Q + I    >(w1);
    const float wp1_1 = wget<Q + I + 1>(w1);

    const bool lo   = (ix0 != mx);           // floor rounded down to mx-1
    const bool edge = (mx == GW - 1);        // x1 clamp at right border

    const float v00 = lo ? wm1_0 : wc_0;
    const float v01 = lo ? wc_0 : (edge ? wc_0 : wp1_0);
    const float v10 = lo ? wm1_1 : wc_1;
    const float v11 = lo ? wc_1 : (edge ? wc_1 : wp1_1);

    const float top = v00 * (1.0f - wx) + v01 * wx;
    const float bot = v10 * (1.0f - wx) + v11 * wx;
    return top * (1.0f - wy) + bot * wy;
}

template <int Q>
__device__ __forceinline__ vfloat4 eval4(const Win12& w0, const Win12& w1,
                                         int mbase, float wy) {
    vfloat4 res;
    res[0] = evalpix<Q, 0>(w0, w1, mbase, wy);
    res[1] = evalpix<Q, 1>(w0, w1, mbase, wy);
    res[2] = evalpix<Q, 2>(w0, w1, mbase, wy);
    res[3] = evalpix<Q, 3>(w0, w1, mbase, wy);
    return res;
}

__global__ __launch_bounds__(256) void grid_sample_k(
    const float* __restrict__ grid,
    const int*   __restrict__ cstart,
    vfloat4*     __restrict__ out4)
{
    // 4096 blocks: one per (channel, grid row). Each thread computes 4 unique
    // pixels of the 1024-wide tile row and stores them to all 16 repeats.
    const int c = blockIdx.x & 3;
    const int g = blockIdx.x >> 2;          // grid row 0..1023

    const int sx = cstart[0];
    const int sy = cstart[1];

    const int oh0 = (g - sy) & (GH - 1);    // first output row for this g

    // y chain (verbatim; my == g)
    constexpr float kInvOff = 1.0f / 511.5f;
    const int my = g;
    const float fy = ((float)my - 511.5f) * kInvOff;
    float y = (fy + 1.0f) * 0.5f * (float)(GH - 1);
    y = fminf(fmaxf(y, 0.0f), (float)(GH - 1));
    const float y0f = floorf(y);
    const float wy  = y - y0f;
    const int   y0  = (int)y0f;
    const int   y1  = min(y0 + 1, GH - 1);

    const float* gp = grid + (size_t)c * (GH * GW);
    const vfloat4* __restrict__ row0 = (const vfloat4*)(gp + (size_t)y0 * GW);
    const vfloat4* __restrict__ row1 = (const vfloat4*)(gp + (size_t)y1 * GW);

    const int tid   = threadIdx.x;
    const int mbase = sx + (tid << 2);      // pre-mod grid col of px 0
    const int B     = (sx >> 2) + tid;      // aligned block index
    const int p     = sx & 3;               // uniform phase

    const int b0 = B & 255;
    const int b1 = (B + 1) & 255;

    vfloat4 res;
    if (p == 0) {
        // window reaches row[mx-1] -> needs block B-1 too (3 blocks)
        const int bm = (B + 255) & 255;
        Win12 w0, w1;
        w0.a = row0[bm]; w0.b = row0[b0]; w0.c = row0[b1];
        w1.a = row1[bm]; w1.b = row1[b0]; w1.c = row1[b1];
        res = eval4<4>(w0, w1, mbase, wy);
    } else {
        Win12 w0, w1;
        w0.a = row0[b0]; w0.b = row0[b1]; w0.c = w0.b;
        w1.a = row1[b0]; w1.b = row1[b1]; w1.c = w1.b;
        if (p == 1)      res = eval4<1>(w0, w1, mbase, wy);
        else if (p == 2) res = eval4<2>(w0, w1, mbase, wy);
        else             res = eval4<3>(w0, w1, mbase, wy);
    }

    // 16 replicated non-temporal stores (4 row-repeats x 4 col-repeats),
    // each wave-coalesced (consecutive tid -> consecutive 16B).
    constexpr int ROW4 = WOUT / 4;          // 1024 vfloat4 per output row
#pragma unroll
    for (int rr = 0; rr < 4; ++rr) {
        const int oh = oh0 + (rr << 10);
        vfloat4* orow = out4 + ((size_t)c * HOUT + oh) * ROW4;
#pragma unroll
        for (int kc = 0; kc < 4; ++kc) {
            __builtin_nontemporal_store(res, &orow[(kc << 8) + tid]);
        }
    }
}

extern "C" void kernel_launch(void* const* d_in, const int* in_sizes, int n_in,
                              void* d_out, int out_size, void* d_ws, size_t ws_size,
                              hipStream_t stream)
{
    const float* grid   = (const float*)d_in[0];
    const int*   cstart = (const int*)d_in[1];
    vfloat4* out = (vfloat4*)d_out;

    const int nblk = C * GH;                // 4096 blocks, one per (c, grid row)
    grid_sample_k<<<nblk, 256, 0, stream>>>(grid, cstart, out);
}

// Round 7
// 277.593 us; speedup vs baseline: 1.6808x; 1.0469x over previous
//
#include <hip/hip_runtime.h>

// grid (1,4,1024,1024) f32 -> out (1,4,4096,4096) f32; cstart int32[2] in [0,512).
constexpr int C    = 4;
constexpr int GH   = 1024;
constexpr int GW   = 1024;
constexpr int HOUT = 4096;
constexpr int WOUT = 4096;

typedef float vfloat4 __attribute__((ext_vector_type(4)));

// R6 post-mortem: replicated-store version runs ~70us (268MB at ~4.0 TB/s).
// Harness fillBuffer proves plain full-line stores hit 6.4 TB/s with FETCH=8KB
// (no RFO on gfx950). R1's high FETCH was grid re-reads, not RFO. So the NT
// flag (no L2 aggregation) is the suspected write-efficiency loss — this
// round: plain stores, single change vs R6.
// Eval chain unchanged since R3 -> bit-identical (absmax 1.525879e-05).

// 12-float window (three vfloat4 blocks); c unused on the 2-block path.
struct Win12 { vfloat4 a, b, c; };
template <int J> __device__ __forceinline__ float wget(const Win12& w) {
    static_assert(J >= 0 && J < 12, "window index");
    if constexpr (J < 4)      return w.a[J];
    else if constexpr (J < 8) return w.b[J - 4];
    else                      return w.c[J - 8];
}

// One output pixel; Q,I compile-time so all wget indices are constants.
// Window invariant: w[Q+I] == row[(mbase+I)&1023].
template <int Q, int I>
__device__ __forceinline__ float evalpix(const Win12& w0, const Win12& w1,
                                         int mbase, float wy) {
    constexpr float kInvOff = 1.0f / 511.5f;
    const int mx = (mbase + I) & (GW - 1);
    const float fx = ((float)mx - 511.5f) * kInvOff;
    float x = (fx + 1.0f) * 0.5f * (float)(GW - 1);
    x = fminf(fmaxf(x, 0.0f), (float)(GW - 1));
    const float x0f = floorf(x);
    const float wx  = x - x0f;
    const int   ix0 = (int)x0f;              // == mx or mx-1 (never <0: x>=0)

    const float wm1_0 = wget<Q + I - 1>(w0);
    const float wc_0  = wget<Q + I    >(w0);
    const float wp1_0 = wget<Q + I + 1>(w0);
    const float wm1_1 = wget<Q + I - 1>(w1);
    const float wc_1  = wget<Q + I    >(w1);
    const float wp1_1 = wget<Q + I + 1>(w1);

    const bool lo   = (ix0 != mx);           // floor rounded down to mx-1
    const bool edge = (mx == GW - 1);        // x1 clamp at right border

    const float v00 = lo ? wm1_0 : wc_0;
    const float v01 = lo ? wc_0 : (edge ? wc_0 : wp1_0);
    const float v10 = lo ? wm1_1 : wc_1;
    const float v11 = lo ? wc_1 : (edge ? wc_1 : wp1_1);

    const float top = v00 * (1.0f - wx) + v01 * wx;
    const float bot = v10 * (1.0f - wx) + v11 * wx;
    return top * (1.0f - wy) + bot * wy;
}

template <int Q>
__device__ __forceinline__ vfloat4 eval4(const Win12& w0, const Win12& w1,
                                         int mbase, float wy) {
    vfloat4 res;
    res[0] = evalpix<Q, 0>(w0, w1, mbase, wy);
    res[1] = evalpix<Q, 1>(w0, w1, mbase, wy);
    res[2] = evalpix<Q, 2>(w0, w1, mbase, wy);
    res[3] = evalpix<Q, 3>(w0, w1, mbase, wy);
    return res;
}

__global__ __launch_bounds__(256) void grid_sample_k(
    const float* __restrict__ grid,
    const int*   __restrict__ cstart,
    vfloat4*     __restrict__ out4)
{
    // 4096 blocks: one per (channel, grid row). Each thread computes 4 unique
    // pixels of the 1024-wide tile row and stores them to all 16 repeats.
    const int c = blockIdx.x & 3;
    const int g = blockIdx.x >> 2;          // grid row 0..1023

    const int sx = cstart[0];
    const int sy = cstart[1];

    const int oh0 = (g - sy) & (GH - 1);    // first output row for this g

    // y chain (verbatim; my == g)
    constexpr float kInvOff = 1.0f / 511.5f;
    const int my = g;
    const float fy = ((float)my - 511.5f) * kInvOff;
    float y = (fy + 1.0f) * 0.5f * (float)(GH - 1);
    y = fminf(fmaxf(y, 0.0f), (float)(GH - 1));
    const float y0f = floorf(y);
    const float wy  = y - y0f;
    const int   y0  = (int)y0f;
    const int   y1  = min(y0 + 1, GH - 1);

    const float* gp = grid + (size_t)c * (GH * GW);
    const vfloat4* __restrict__ row0 = (const vfloat4*)(gp + (size_t)y0 * GW);
    const vfloat4* __restrict__ row1 = (const vfloat4*)(gp + (size_t)y1 * GW);

    const int tid   = threadIdx.x;
    const int mbase = sx + (tid << 2);      // pre-mod grid col of px 0
    const int B     = (sx >> 2) + tid;      // aligned block index
    const int p     = sx & 3;               // uniform phase

    const int b0 = B & 255;
    const int b1 = (B + 1) & 255;

    vfloat4 res;
    if (p == 0) {
        // window reaches row[mx-1] -> needs block B-1 too (3 blocks)
        const int bm = (B + 255) & 255;
        Win12 w0, w1;
        w0.a = row0[bm]; w0.b = row0[b0]; w0.c = row0[b1];
        w1.a = row1[bm]; w1.b = row1[b0]; w1.c = row1[b1];
        res = eval4<4>(w0, w1, mbase, wy);
    } else {
        Win12 w0, w1;
        w0.a = row0[b0]; w0.b = row0[b1]; w0.c = w0.b;
        w1.a = row1[b0]; w1.b = row1[b1]; w1.c = w1.b;
        if (p == 1)      res = eval4<1>(w0, w1, mbase, wy);
        else if (p == 2) res = eval4<2>(w0, w1, mbase, wy);
        else             res = eval4<3>(w0, w1, mbase, wy);
    }

    // 16 replicated stores (4 row-repeats x 4 col-repeats), each
    // wave-coalesced (consecutive tid -> consecutive 16B). Plain stores:
    // full-line write-combine in L2 (no RFO per fillBuffer counter evidence),
    // streams at ~6.4 TB/s vs NT's ~4.0.
    constexpr int ROW4 = WOUT / 4;          // 1024 vfloat4 per output row
#pragma unroll
    for (int rr = 0; rr < 4; ++rr) {
        const int oh = oh0 + (rr << 10);
        vfloat4* orow = out4 + ((size_t)c * HOUT + oh) * ROW4;
#pragma unroll
        for (int kc = 0; kc < 4; ++kc) {
            orow[(kc << 8) + tid] = res;
        }
    }
}

extern "C" void kernel_launch(void* const* d_in, const int* in_sizes, int n_in,
                              void* d_out, int out_size, void* d_ws, size_t ws_size,
                              hipStream_t stream)
{
    const float* grid   = (const float*)d_in[0];
    const int*   cstart = (const int*)d_in[1];
    vfloat4* out = (vfloat4*)d_out;

    const int nblk = C * GH;                // 4096 blocks, one per (c, grid row)
    grid_sample_k<<<nblk, 256, 0, stream>>>(grid, cstart, out);
}